// Round 18
// baseline (214.817 us; speedup 1.0000x reference)
//
#include <hip/hip_runtime.h>

#define TT 16
#define CC 320
#define NHEADS 8
#define DH 64
#define INNER 512

typedef float f32x4 __attribute__((ext_vector_type(4)));
typedef float f32x16 __attribute__((ext_vector_type(16)));
typedef short bf16x8 __attribute__((ext_vector_type(8)));
typedef unsigned short u16;

#define Z16 {0.f,0.f,0.f,0.f,0.f,0.f,0.f,0.f,0.f,0.f,0.f,0.f,0.f,0.f,0.f,0.f}

__device__ __forceinline__ float bf2f(u16 u){
    union { unsigned int i; float f; } v; v.i = ((unsigned int)u) << 16; return v.f;
}
__device__ __forceinline__ u16 f2bf(float f){
    union { float f; unsigned int i; } v; v.f = f;
    unsigned int x = v.i;
    return (u16)((x + 0x7fffu + ((x >> 16) & 1u)) >> 16);   // RNE
}

// ---------------- kernel 1: merged prep (weight frags + LayerNorm) ----------------
// blk <  240 : Wq/Wk/Wv -> bf16 32x32x16-frag, 24KB-CHUNK-major (R6 layout):
//              frag f = ((hd*5 + c)*6 + nblk)*4 + kl ; kk = c*4 + kl
//              nblk 0,1=Q 2,3=K 4,5=V. lane = ((k%16)>>3)*32 + (n%32), elem=k%8.
// blk <  320 : Wo -> bf16 32x32x16-frag-major: frag f = nb*32 + kt.
// blk >= 320 : transpose + LayerNorm -> xn bf16 32x32x16 A-frag-major (wg = blk-320).
__global__ __launch_bounds__(256) void k_prep(const float* __restrict__ wq, const float* __restrict__ wk,
                                              const float* __restrict__ wv, const float* __restrict__ wo,
                                              const float* __restrict__ lnw, const float* __restrict__ lnb,
                                              const float* __restrict__ x,
                                              u16* __restrict__ dqkv, u16* __restrict__ dwo,
                                              u16* __restrict__ xnf){
    __shared__ float tile[CC][37];
    __shared__ float psum[32][36];
    __shared__ float psq[32][36];
    __shared__ float meanb[32];
    __shared__ float rstdb[32];
    __shared__ float lnw_s[CC];
    __shared__ float lnb_s[CC];

    int blk = blockIdx.x;
    int tid = threadIdx.x;

    if (blk < 240){
        int gid  = blk * 256 + tid;                   // 0..61439
        int lane = gid & 63;
        int f    = gid >> 6;                          // 0..959
        int kl   = f & 3;
        int nblk = (f >> 2) % 6;
        int c    = ((f >> 2) / 6) % 5;
        int hd   = f / 120;
        int kk   = c * 4 + kl;
        const float* W = (nblk < 2) ? wq : (nblk < 4) ? wk : wv;
        int n  = hd * DH + (nblk & 1) * 32 + (lane & 31);
        int k0 = kk * 16 + (lane >> 5) * 8;
        const float* src = W + (size_t)n * CC + k0;
        f32x4 v0 = *(const f32x4*)src;
        f32x4 v1 = *(const f32x4*)(src + 4);
        bf16x8 o;
        o[0] = (short)f2bf(v0[0]); o[1] = (short)f2bf(v0[1]);
        o[2] = (short)f2bf(v0[2]); o[3] = (short)f2bf(v0[3]);
        o[4] = (short)f2bf(v1[0]); o[5] = (short)f2bf(v1[1]);
        o[6] = (short)f2bf(v1[2]); o[7] = (short)f2bf(v1[3]);
        *(bf16x8*)(dqkv + (size_t)gid * 8) = o;
        return;
    }
    if (blk < 320){
        int gid  = (blk - 240) * 256 + tid;           // 0..20479
        int lane = gid & 63;
        int f    = gid >> 6;                          // 0..319
        int kt   = f & 31;
        int nb   = f >> 5;
        int n  = nb * 32 + (lane & 31);
        int k0 = kt * 16 + (lane >> 5) * 8;
        const float* src = wo + (size_t)n * INNER + k0;
        f32x4 v0 = *(const f32x4*)src;
        f32x4 v1 = *(const f32x4*)(src + 4);
        bf16x8 o;
        o[0] = (short)f2bf(v0[0]); o[1] = (short)f2bf(v0[1]);
        o[2] = (short)f2bf(v0[2]); o[3] = (short)f2bf(v0[3]);
        o[4] = (short)f2bf(v1[0]); o[5] = (short)f2bf(v1[1]);
        o[6] = (short)f2bf(v1[2]); o[7] = (short)f2bf(v1[3]);
        *(bf16x8*)(dwo + (size_t)gid * 8) = o;
        return;
    }

    // ---- LayerNorm branch ----
    int wg = blk - 320;                  // (b,h,t)
    int t = wg & 15, h = (wg >> 4) & 31, b = wg >> 9;
    const size_t base = ((size_t)(b * CC) * TT + t) * 1024 + h * 32;

    if (tid < CC - 256){ lnw_s[256 + tid] = lnw[256 + tid]; lnb_s[256 + tid] = lnb[256 + tid]; }
    lnw_s[tid] = lnw[tid]; lnb_s[tid] = lnb[tid];

    int w4 = (tid & 7) * 4, cg = tid >> 3;
    f32x4 s4 = {0.f,0.f,0.f,0.f}, q4 = {0.f,0.f,0.f,0.f};
    for (int i = 0; i < 10; ++i){
        int c = cg * 10 + i;
        f32x4 v = *(const f32x4*)(x + base + (size_t)c * 16384 + w4);
        tile[c][w4 + 0] = v[0]; tile[c][w4 + 1] = v[1];
        tile[c][w4 + 2] = v[2]; tile[c][w4 + 3] = v[3];
        s4 += v; q4 += v * v;
    }
    psum[cg][w4 + 0] = s4[0]; psum[cg][w4 + 1] = s4[1]; psum[cg][w4 + 2] = s4[2]; psum[cg][w4 + 3] = s4[3];
    psq [cg][w4 + 0] = q4[0]; psq [cg][w4 + 1] = q4[1]; psq [cg][w4 + 2] = q4[2]; psq [cg][w4 + 3] = q4[3];
    __syncthreads();

    if (tid < 32){
        float s = 0.f, q = 0.f;
        for (int g = 0; g < 32; ++g){ s += psum[g][tid]; q += psq[g][tid]; }
        float mean = s * (1.f / CC);
        float var  = q * (1.f / CC) - mean * mean;
        meanb[tid] = mean;
        rstdb[tid] = rsqrtf(var + 1e-5f);
    }
    __syncthreads();

    int s_base = (b * 32 + h) * 32;
    #pragma unroll
    for (int j = 0; j < 5; ++j){
        int u = tid + 256 * j;              // 0..1279
        int w = u / 40, c8 = u % 40;
        float mean = meanb[w], rstd = rstdb[w];
        int s = s_base + w;
        int row = ((s & 1) << 4) | t;
        int kk = c8 >> 1;
        int lane_f = ((c8 & 1) << 5) | row;
        size_t m32 = (size_t)(s >> 1);
        bf16x8 o;
        #pragma unroll
        for (int e = 0; e < 8; ++e){
            int c = c8 * 8 + e;
            float nv = (tile[c][w] - mean) * rstd * lnw_s[c] + lnb_s[c];
            o[e] = (short)f2bf(nv);
        }
        *(bf16x8*)(xnf + ((size_t)(m32 * 20 + kk) * 64 + lane_f) * 8) = o;
    }
}

// ---------------- kernel 2: fused QKV + attention — dual 24KB prefetch buffers ----------------
// 512 thr = 8 waves; wave owns one 32-row m-tile (2 samples), xn A-frags in regs.
// Per head: 5 chunks of 24KB. Chunks 0 AND 1 of head hd+1 prefetched into dedicated
// pbuf0/pbuf1 during head hd's attention phase; in-loop: ch2->buf0 @c0, ch3->buf1 @c1,
// ch4->pbuf0 @c2 — every drain waits on a stage issued >=1 full chunk earlier.
// vt pad keys come from predicated zero registers (R17). LDS 156KB -> 1 WG/CU.
#define QH(w,s,r,c) smem[((((w)*2+(s))*16+(r))*72) + (c)]
#define KH(w,s,r,c) smem[18432 + ((((w)*2+(s))*16+(r))*72) + (c)]
#define VT(w,s,d,k) smem[36864 + ((((w)*2+(s))*64+(d))*18) + (k)]

__global__ __launch_bounds__(512, 2) void k_attn(const u16* __restrict__ xnf,
                                                 const u16* __restrict__ wqkv,
                                                 u16* __restrict__ aot){
    // u16 idx: qh [0,18432) kh [18432,36864) vt [36864,55296)
    //          pbuf0 [55296,67584) pbuf1 [67584,79872)   -> 159,744 B total (<=160KB)
    // weight double-buffer overlays qh+kh: buf0 = [0,12288), buf1 = [12288,24576)
    __shared__ u16 smem[79872];

    const int tid  = threadIdx.x;
    const int lane = tid & 63;
    const int wid  = tid >> 6;        // 0..7
    const int l31  = lane & 31;
    const int h32  = lane >> 5;
    const int l15  = lane & 15;
    const int g4   = lane >> 4;
    const int m32  = blockIdx.x * 8 + wid;
    const f32x4 zero4 = {0.f, 0.f, 0.f, 0.f};
    const bf16x8 zero8 = {0, 0, 0, 0, 0, 0, 0, 0};

    // stage: chunk c of head hd -> dst (u16* in LDS); 512thr x 3 x 16B = 24KB (12288 u16)
    #define STAGE_TO(hd_, c_, dst_) do {                                               \
        const u16* gsrc_ = wqkv + ((size_t)((hd_) * 5 + (c_)) * 12288);                \
        u16* ldst_ = (dst_);                                                           \
        _Pragma("unroll")                                                              \
        for (int i_ = 0; i_ < 3; ++i_)                                                 \
            __builtin_amdgcn_global_load_lds(                                          \
                (const __attribute__((address_space(1))) void*)(gsrc_ + (tid + i_ * 512) * 8), \
                (__attribute__((address_space(3))) void*)(ldst_ + (tid + i_ * 512) * 8),       \
                16, 0, 0);                                                             \
    } while (0)

    // prologue: prefetch head 0 chunks 0,1 into pbufs (fly during a_f loads)
    STAGE_TO(0, 0, (u16*)smem + 55296);
    STAGE_TO(0, 1, (u16*)smem + 67584);

    // persistent A-frags (this wave's 32 rows x 320 K), coalesced frag loads
    bf16x8 a_f[20];
    {
        const u16* xp = xnf + ((size_t)m32 * 20 * 64 + lane) * 8;
        #pragma unroll
        for (int kk = 0; kk < 20; ++kk)
            a_f[kk] = *(const bf16x8*)(xp + kk * 512);
    }

    for (int hd = 0; hd < NHEADS; ++hd){
        // all waves done reading qh/kh (attn of prev head) before in-loop staging clobbers them
        __builtin_amdgcn_sched_barrier(0);
        __builtin_amdgcn_s_barrier();
        __builtin_amdgcn_sched_barrier(0);

        f32x16 acc[6];
        #pragma unroll
        for (int nb = 0; nb < 6; ++nb) acc[nb] = (f32x16)Z16;

        #pragma unroll
        for (int c = 0; c < 5; ++c){
            // drain: every stage waited on here was issued >=1 full chunk (or a whole
            // attention phase) earlier
            asm volatile("s_waitcnt vmcnt(0)" ::: "memory");
            __builtin_amdgcn_sched_barrier(0);
            __builtin_amdgcn_s_barrier();      // chunk c visible from all waves
            __builtin_amdgcn_sched_barrier(0);
            if      (c == 0) STAGE_TO(hd, 2, (u16*)smem);            // ch2 -> buf0
            else if (c == 1) STAGE_TO(hd, 3, (u16*)smem + 12288);    // ch3 -> buf1
            else if (c == 2) STAGE_TO(hd, 4, (u16*)smem + 55296);    // ch4 -> pbuf0 (read @c0, 2 barriers ago)
            const u16* wb = (c == 0) ? (const u16*)smem + 55296      // pbuf0
                          : (c == 1) ? (const u16*)smem + 67584      // pbuf1
                          : (c == 2) ? (const u16*)smem              // buf0
                          : (c == 3) ? (const u16*)smem + 12288      // buf1
                                     : (const u16*)smem + 55296;     // pbuf0 (ch4)
            #pragma unroll
            for (int kl = 0; kl < 4; ++kl){
                #pragma unroll
                for (int nb = 0; nb < 6; ++nb){
                    bf16x8 b = *(const bf16x8*)(wb + (nb * 4 + kl) * 512 + lane * 8);
                    acc[nb] = __builtin_amdgcn_mfma_f32_32x32x16_bf16(a_f[c * 4 + kl], b, acc[nb], 0, 0, 0);
                }
            }
            __builtin_amdgcn_sched_barrier(0);
            __builtin_amdgcn_s_barrier();      // all waves done reading this chunk's buffer
            __builtin_amdgcn_sched_barrier(0);
        }

        // prefetch NEXT head's chunks 0,1 into pbufs — fly during unpack + attention
        // (pbuf0 last read @c4, separated by c4's trailing barrier; pbuf1 last read @c1)
        if (hd < NHEADS - 1){
            STAGE_TO(hd + 1, 0, (u16*)smem + 55296);
            STAGE_TO(hd + 1, 1, (u16*)smem + 67584);
        }

        // ---- unpack QKV accumulators to wave-private LDS slices ----
        #pragma unroll
        for (int r = 0; r < 16; ++r){
            int row = (r & 3) + 8 * (r >> 2) + 4 * h32;   // verified 32x32 C layout
            int smp = row >> 4, tr = row & 15;
            QH(wid, smp, tr, l31)      = f2bf(acc[0][r] * 0.125f);   // pre-scale 1/sqrt(64)
            QH(wid, smp, tr, 32 + l31) = f2bf(acc[1][r] * 0.125f);
            KH(wid, smp, tr, l31)      = f2bf(acc[2][r]);
            KH(wid, smp, tr, 32 + l31) = f2bf(acc[3][r]);
            VT(wid, smp, l31, tr)      = f2bf(acc[4][r]);            // V^T: [d][key16]
            VT(wid, smp, 32 + l31, tr) = f2bf(acc[5][r]);
        }

        // ---- attention, per owned sample (wave-private, no barriers) ----
        #pragma unroll
        for (int smp = 0; smp < 2; ++smp){
            f32x4 sc = zero4;
            #pragma unroll
            for (int k0 = 0; k0 < DH; k0 += 32){
                bf16x8 qa = *(const bf16x8*)&QH(wid, smp, l15, k0 + g4 * 8);
                bf16x8 kb = *(const bf16x8*)&KH(wid, smp, l15, k0 + g4 * 8);
                sc = __builtin_amdgcn_mfma_f32_16x16x32_bf16(qa, kb, sc, 0, 0, 0);
            }
            f32x4 pr;
            #pragma unroll
            for (int r = 0; r < 4; ++r){
                float m = sc[r];
                m = fmaxf(m, __shfl_xor(m, 1)); m = fmaxf(m, __shfl_xor(m, 2));
                m = fmaxf(m, __shfl_xor(m, 4)); m = fmaxf(m, __shfl_xor(m, 8));
                float e = __expf(sc[r] - m);
                float ss = e;
                ss += __shfl_xor(ss, 1); ss += __shfl_xor(ss, 2);
                ss += __shfl_xor(ss, 4); ss += __shfl_xor(ss, 8);
                pr[r] = e / ss;
            }
            // P -> qh cols 0..15 (Q dead); pad keys 16..31 come from predicated zero regs
            #pragma unroll
            for (int r = 0; r < 4; ++r)
                QH(wid, smp, g4 * 4 + r, l15) = f2bf(pr[r]);

            // PV (K=32; keys 16..31 zero via predication: lane groups 2,3 keep zero regs)
            bf16x8 pa = zero8;
            if (g4 < 2) pa = *(const bf16x8*)&QH(wid, smp, l15, g4 * 8);
            #pragma unroll
            for (int nb = 0; nb < 4; ++nb){
                bf16x8 vb = zero8;
                if (g4 < 2) vb = *(const bf16x8*)&VT(wid, smp, nb * 16 + l15, g4 * 8);
                f32x4 at = __builtin_amdgcn_mfma_f32_16x16x32_bf16(pa, vb, zero4, 0, 0, 0);
                #pragma unroll
                for (int r = 0; r < 4; ++r)
                    KH(wid, smp, g4 * 4 + r, nb * 16 + l15) = f2bf(at[r]);
            }
            // store attn-out to aot[t][sample][k]: 16 x 64B segments per store op
            const size_t sg = (size_t)m32 * 2 + smp;
            #pragma unroll
            for (int kkl = 0; kkl < 2; ++kkl){
                bf16x8 o8 = *(const bf16x8*)&KH(wid, smp, l15, kkl * 32 + g4 * 8);
                *(bf16x8*)(aot + ((size_t)l15 * 4096 + sg) * 512 + hd * 64 + kkl * 32 + g4 * 8) = o8;
            }
        }
    }
    #undef STAGE_TO
}

// ---------------- kernel 3: fused O-proj + bias + residual + transpose-out ----------------
__global__ __launch_bounds__(256) void k_oproj_res(const u16* __restrict__ aot, const u16* __restrict__ wof,
                                                   const float* __restrict__ bo, const float* __restrict__ x,
                                                   float* __restrict__ out){
    __shared__ u16 atile[32 * 516];       // [sample][k], row stride 516 (2-way-free)
    __shared__ float otile[4][32 * 36];   // per-wave [c][w], row stride 36

    const int tid  = threadIdx.x;
    const int lane = tid & 63;
    const int wid  = tid >> 6;            // 0..3
    const int l31  = lane & 31;
    const int h32  = lane >> 5;
    int wg = blockIdx.x;                  // (b,h,t)
    int t = wg & 15, h = (wg >> 4) & 31, b = wg >> 9;
    const int s0 = (b * 32 + h) * 32;

    // stage A: 32 rows x 512 (32KB contiguous in aot) -> padded LDS (reg-staged)
    {
        const u16* src = aot + ((size_t)t * 4096 + s0) * 512;
        #pragma unroll
        for (int i = 0; i < 8; ++i){
            int flat = tid + 256 * i;          // 0..2047
            int row = flat >> 6, c16 = flat & 63;
            bf16x8 v = *(const bf16x8*)(src + (size_t)flat * 8);
            *(bf16x8*)(atile + row * 516 + c16 * 8) = v;
        }
    }
    __syncthreads();

    // wave's c-block range: 3/3/2/2
    const int nb_start = (wid < 2) ? wid * 3 : 6 + (wid - 2) * 2;
    const int nb_count = (wid < 2) ? 3 : 2;

    for (int j = 0; j < nb_count; ++j){
        const int nb = nb_start + j;
        f32x16 acc = (f32x16)Z16;
        const u16* wp = wof + ((size_t)(nb * 32) * 64 + lane) * 8;
        #pragma unroll
        for (int kt = 0; kt < 32; ++kt){
            bf16x8 af = *(const bf16x8*)(atile + l31 * 516 + kt * 16 + h32 * 8);
            bf16x8 bf = *(const bf16x8*)(wp + (size_t)kt * 512);
            acc = __builtin_amdgcn_mfma_f32_32x32x16_bf16(af, bf, acc, 0, 0, 0);
        }
        // C layout: col = l31 (c within block), row = (r&3)+8*(r>>2)+4*h32 (= w)
        float bias_v = bo[nb * 32 + l31];
        #pragma unroll
        for (int r = 0; r < 16; ++r){
            int row = (r & 3) + 8 * (r >> 2) + 4 * h32;
            otile[wid][l31 * 36 + row] = acc[r] + bias_v;
        }
        // residual + coalesced float4 write along w (same wave; compiler orders LDS RAW)
        int cl = lane >> 3;                   // 0..7
        int w4 = (lane & 7) * 4;
        #pragma unroll
        for (int ci = 0; ci < 4; ++ci){
            int c = ci * 8 + cl;
            size_t idx = ((size_t)(b * CC + nb * 32 + c) * TT + t) * 1024 + h * 32 + w4;
            f32x4 ov = *(const f32x4*)(&otile[wid][c * 36 + w4]);
            f32x4 xv = *(const f32x4*)(x + idx);
            *(f32x4*)(out + idx) = xv + ov;
        }
    }
}

extern "C" void kernel_launch(void* const* d_in, const int* in_sizes, int n_in,
                              void* d_out, int out_size, void* d_ws, size_t ws_size,
                              hipStream_t stream){
    const float* hid = (const float*)d_in[0];
    const float* lnw = (const float*)d_in[1];
    const float* lnb = (const float*)d_in[2];
    const float* Wq  = (const float*)d_in[3];
    const float* Wk  = (const float*)d_in[4];
    const float* Wv  = (const float*)d_in[5];
    const float* Wo  = (const float*)d_in[6];
    const float* bo  = (const float*)d_in[7];

    char* ws = (char*)d_ws;
    u16* wqkv = (u16*)ws;                                   // 960 frags * 512 = 491,520 elems
    u16* wo_f = wqkv + (size_t)960 * 512;                   // 320 frags * 512 = 163,840 elems
    u16* aot  = wo_f + 163840;                              // 16*4096*512 (67 MB), [t][sample][k]
    u16* xn   = aot + (size_t)TT * 4096 * INNER;            // 65536*320 (40 MB), 32-frag-major

    k_prep     <<<2368, 256, 0, stream>>>(Wq, Wk, Wv, Wo, lnw, lnb, hid, wqkv, wo_f, xn);
    k_attn     <<<256, 512, 0, stream>>>(xn, wqkv, aot);
    k_oproj_res<<<2048, 256, 0, stream>>>(aot, wo_f, bo, hid, (float*)d_out);
}

// Round 19
// 194.925 us; speedup vs baseline: 1.1020x; 1.1020x over previous
//
#include <hip/hip_runtime.h>

#define TT 16
#define CC 320
#define NHEADS 8
#define DH 64
#define INNER 512

typedef float f32x4 __attribute__((ext_vector_type(4)));
typedef float f32x16 __attribute__((ext_vector_type(16)));
typedef short bf16x8 __attribute__((ext_vector_type(8)));
typedef unsigned short u16;

#define Z16 {0.f,0.f,0.f,0.f,0.f,0.f,0.f,0.f,0.f,0.f,0.f,0.f,0.f,0.f,0.f,0.f}

__device__ __forceinline__ float bf2f(u16 u){
    union { unsigned int i; float f; } v; v.i = ((unsigned int)u) << 16; return v.f;
}
__device__ __forceinline__ u16 f2bf(float f){
    union { float f; unsigned int i; } v; v.f = f;
    unsigned int x = v.i;
    return (u16)((x + 0x7fffu + ((x >> 16) & 1u)) >> 16);   // RNE
}

// ---------------- kernel 1: merged prep (weight frags + LayerNorm) ----------------
// blk <  240 : Wq/Wk/Wv -> bf16 32x32x16-frag, 24KB-CHUNK-major (R6 layout):
//              frag f = ((hd*5 + c)*6 + nblk)*4 + kl ; kk = c*4 + kl
//              nblk 0,1=Q 2,3=K 4,5=V. lane = ((k%16)>>3)*32 + (n%32), elem=k%8.
// blk <  320 : Wo -> bf16 32x32x16-frag-major: frag f = nb*32 + kt.
// blk >= 320 : transpose + LayerNorm -> xn bf16 32x32x16 A-frag-major (wg = blk-320).
__global__ __launch_bounds__(256) void k_prep(const float* __restrict__ wq, const float* __restrict__ wk,
                                              const float* __restrict__ wv, const float* __restrict__ wo,
                                              const float* __restrict__ lnw, const float* __restrict__ lnb,
                                              const float* __restrict__ x,
                                              u16* __restrict__ dqkv, u16* __restrict__ dwo,
                                              u16* __restrict__ xnf){
    __shared__ float tile[CC][37];
    __shared__ float psum[32][36];
    __shared__ float psq[32][36];
    __shared__ float meanb[32];
    __shared__ float rstdb[32];
    __shared__ float lnw_s[CC];
    __shared__ float lnb_s[CC];

    int blk = blockIdx.x;
    int tid = threadIdx.x;

    if (blk < 240){
        int gid  = blk * 256 + tid;                   // 0..61439
        int lane = gid & 63;
        int f    = gid >> 6;                          // 0..959
        int kl   = f & 3;
        int nblk = (f >> 2) % 6;
        int c    = ((f >> 2) / 6) % 5;
        int hd   = f / 120;
        int kk   = c * 4 + kl;
        const float* W = (nblk < 2) ? wq : (nblk < 4) ? wk : wv;
        int n  = hd * DH + (nblk & 1) * 32 + (lane & 31);
        int k0 = kk * 16 + (lane >> 5) * 8;
        const float* src = W + (size_t)n * CC + k0;
        f32x4 v0 = *(const f32x4*)src;
        f32x4 v1 = *(const f32x4*)(src + 4);
        bf16x8 o;
        o[0] = (short)f2bf(v0[0]); o[1] = (short)f2bf(v0[1]);
        o[2] = (short)f2bf(v0[2]); o[3] = (short)f2bf(v0[3]);
        o[4] = (short)f2bf(v1[0]); o[5] = (short)f2bf(v1[1]);
        o[6] = (short)f2bf(v1[2]); o[7] = (short)f2bf(v1[3]);
        *(bf16x8*)(dqkv + (size_t)gid * 8) = o;
        return;
    }
    if (blk < 320){
        int gid  = (blk - 240) * 256 + tid;           // 0..20479
        int lane = gid & 63;
        int f    = gid >> 6;                          // 0..319
        int kt   = f & 31;
        int nb   = f >> 5;
        int n  = nb * 32 + (lane & 31);
        int k0 = kt * 16 + (lane >> 5) * 8;
        const float* src = wo + (size_t)n * INNER + k0;
        f32x4 v0 = *(const f32x4*)src;
        f32x4 v1 = *(const f32x4*)(src + 4);
        bf16x8 o;
        o[0] = (short)f2bf(v0[0]); o[1] = (short)f2bf(v0[1]);
        o[2] = (short)f2bf(v0[2]); o[3] = (short)f2bf(v0[3]);
        o[4] = (short)f2bf(v1[0]); o[5] = (short)f2bf(v1[1]);
        o[6] = (short)f2bf(v1[2]); o[7] = (short)f2bf(v1[3]);
        *(bf16x8*)(dwo + (size_t)gid * 8) = o;
        return;
    }

    // ---- LayerNorm branch ----
    int wg = blk - 320;                  // (b,h,t)
    int t = wg & 15, h = (wg >> 4) & 31, b = wg >> 9;
    const size_t base = ((size_t)(b * CC) * TT + t) * 1024 + h * 32;

    if (tid < CC - 256){ lnw_s[256 + tid] = lnw[256 + tid]; lnb_s[256 + tid] = lnb[256 + tid]; }
    lnw_s[tid] = lnw[tid]; lnb_s[tid] = lnb[tid];

    int w4 = (tid & 7) * 4, cg = tid >> 3;
    f32x4 s4 = {0.f,0.f,0.f,0.f}, q4 = {0.f,0.f,0.f,0.f};
    for (int i = 0; i < 10; ++i){
        int c = cg * 10 + i;
        f32x4 v = *(const f32x4*)(x + base + (size_t)c * 16384 + w4);
        tile[c][w4 + 0] = v[0]; tile[c][w4 + 1] = v[1];
        tile[c][w4 + 2] = v[2]; tile[c][w4 + 3] = v[3];
        s4 += v; q4 += v * v;
    }
    psum[cg][w4 + 0] = s4[0]; psum[cg][w4 + 1] = s4[1]; psum[cg][w4 + 2] = s4[2]; psum[cg][w4 + 3] = s4[3];
    psq [cg][w4 + 0] = q4[0]; psq [cg][w4 + 1] = q4[1]; psq [cg][w4 + 2] = q4[2]; psq [cg][w4 + 3] = q4[3];
    __syncthreads();

    if (tid < 32){
        float s = 0.f, q = 0.f;
        for (int g = 0; g < 32; ++g){ s += psum[g][tid]; q += psq[g][tid]; }
        float mean = s * (1.f / CC);
        float var  = q * (1.f / CC) - mean * mean;
        meanb[tid] = mean;
        rstdb[tid] = rsqrtf(var + 1e-5f);
    }
    __syncthreads();

    int s_base = (b * 32 + h) * 32;
    #pragma unroll
    for (int j = 0; j < 5; ++j){
        int u = tid + 256 * j;              // 0..1279
        int w = u / 40, c8 = u % 40;
        float mean = meanb[w], rstd = rstdb[w];
        int s = s_base + w;
        int row = ((s & 1) << 4) | t;
        int kk = c8 >> 1;
        int lane_f = ((c8 & 1) << 5) | row;
        size_t m32 = (size_t)(s >> 1);
        bf16x8 o;
        #pragma unroll
        for (int e = 0; e < 8; ++e){
            int c = c8 * 8 + e;
            float nv = (tile[c][w] - mean) * rstd * lnw_s[c] + lnb_s[c];
            o[e] = (short)f2bf(nv);
        }
        *(bf16x8*)(xnf + ((size_t)(m32 * 20 + kk) * 64 + lane_f) * 8) = o;
    }
}

// ---------------- kernel 2: fused QKV + attention — R17-exact (best: 95.7-97.0us) ----------------
// 512 thr = 8 waves; wave owns one 32-row m-tile (2 samples), xn A-frags in regs.
// Per head: 5 chunks of 24KB. Chunk 0 of head hd+1 prefetched into a dedicated 24KB pbuf
// during head hd's attention phase; chunks 1..4 double-buffer in the qh/kh overlay.
// vt shrunk 72->36KB: the PV K=32 zero-pad (keys 16..31) comes from PREDICATED ZERO
// REGISTERS (lane groups g4>=2 skip the LDS read) instead of stored zeros.
// LDS 132KB -> 1 WG/CU.
#define QH(w,s,r,c) smem[((((w)*2+(s))*16+(r))*72) + (c)]
#define KH(w,s,r,c) smem[18432 + ((((w)*2+(s))*16+(r))*72) + (c)]
#define VT(w,s,d,k) smem[36864 + ((((w)*2+(s))*64+(d))*18) + (k)]

__global__ __launch_bounds__(512, 2) void k_attn(const u16* __restrict__ xnf,
                                                 const u16* __restrict__ wqkv,
                                                 u16* __restrict__ aot){
    // u16 idx: qh [0,18432) kh [18432,36864) vt [36864,55296) pbuf [55296,67584)
    // weight double-buffer overlays qh+kh: buf0 = [0,12288), buf1 = [12288,24576)
    __shared__ u16 smem[67584];   // 135,168 B

    const int tid  = threadIdx.x;
    const int lane = tid & 63;
    const int wid  = tid >> 6;        // 0..7
    const int l31  = lane & 31;
    const int h32  = lane >> 5;
    const int l15  = lane & 15;
    const int g4   = lane >> 4;
    const int m32  = blockIdx.x * 8 + wid;
    const f32x4 zero4 = {0.f, 0.f, 0.f, 0.f};
    const bf16x8 zero8 = {0, 0, 0, 0, 0, 0, 0, 0};

    // stage: chunk c of head hd -> dst (u16* in LDS); 512thr x 3 x 16B = 24KB (12288 u16)
    #define STAGE_TO(hd_, c_, dst_) do {                                               \
        const u16* gsrc_ = wqkv + ((size_t)((hd_) * 5 + (c_)) * 12288);                \
        u16* ldst_ = (dst_);                                                           \
        _Pragma("unroll")                                                              \
        for (int i_ = 0; i_ < 3; ++i_)                                                 \
            __builtin_amdgcn_global_load_lds(                                          \
                (const __attribute__((address_space(1))) void*)(gsrc_ + (tid + i_ * 512) * 8), \
                (__attribute__((address_space(3))) void*)(ldst_ + (tid + i_ * 512) * 8),       \
                16, 0, 0);                                                             \
    } while (0)

    // prologue: prefetch head 0 chunk 0 into pbuf (flies during a_f loads)
    STAGE_TO(0, 0, (u16*)smem + 55296);

    // persistent A-frags (this wave's 32 rows x 320 K), coalesced frag loads
    bf16x8 a_f[20];
    {
        const u16* xp = xnf + ((size_t)m32 * 20 * 64 + lane) * 8;
        #pragma unroll
        for (int kk = 0; kk < 20; ++kk)
            a_f[kk] = *(const bf16x8*)(xp + kk * 512);
    }

    for (int hd = 0; hd < NHEADS; ++hd){
        // all waves done reading qh/kh (attn of prev head) before chunk>=1 staging clobbers them
        __builtin_amdgcn_sched_barrier(0);
        __builtin_amdgcn_s_barrier();
        __builtin_amdgcn_sched_barrier(0);

        f32x16 acc[6];
        #pragma unroll
        for (int nb = 0; nb < 6; ++nb) acc[nb] = (f32x16)Z16;

        #pragma unroll
        for (int c = 0; c < 5; ++c){
            // drain staging (chunk 0 flew during prev head's attention; others during compute c-1)
            asm volatile("s_waitcnt vmcnt(0)" ::: "memory");
            __builtin_amdgcn_sched_barrier(0);
            __builtin_amdgcn_s_barrier();      // chunk c visible from all waves
            __builtin_amdgcn_sched_barrier(0);
            if (c < 4) STAGE_TO(hd, c + 1, (u16*)smem + ((c + 1) & 1) * 12288);  // prefetch next chunk
            const u16* wb = (c == 0) ? (const u16*)smem + 55296
                                     : (const u16*)smem + (c & 1) * 12288;
            #pragma unroll
            for (int kl = 0; kl < 4; ++kl){
                #pragma unroll
                for (int nb = 0; nb < 6; ++nb){
                    bf16x8 b = *(const bf16x8*)(wb + (nb * 4 + kl) * 512 + lane * 8);
                    acc[nb] = __builtin_amdgcn_mfma_f32_32x32x16_bf16(a_f[c * 4 + kl], b, acc[nb], 0, 0, 0);
                }
            }
            __builtin_amdgcn_sched_barrier(0);
            __builtin_amdgcn_s_barrier();      // all waves done reading this chunk's buffer
            __builtin_amdgcn_sched_barrier(0);
        }

        // prefetch NEXT head's chunk 0 into pbuf — flies during unpack + attention
        if (hd < NHEADS - 1) STAGE_TO(hd + 1, 0, (u16*)smem + 55296);

        // ---- unpack QKV accumulators to wave-private LDS slices ----
        #pragma unroll
        for (int r = 0; r < 16; ++r){
            int row = (r & 3) + 8 * (r >> 2) + 4 * h32;   // verified 32x32 C layout
            int smp = row >> 4, tr = row & 15;
            QH(wid, smp, tr, l31)      = f2bf(acc[0][r] * 0.125f);   // pre-scale 1/sqrt(64)
            QH(wid, smp, tr, 32 + l31) = f2bf(acc[1][r] * 0.125f);
            KH(wid, smp, tr, l31)      = f2bf(acc[2][r]);
            KH(wid, smp, tr, 32 + l31) = f2bf(acc[3][r]);
            VT(wid, smp, l31, tr)      = f2bf(acc[4][r]);            // V^T: [d][key16]
            VT(wid, smp, 32 + l31, tr) = f2bf(acc[5][r]);
        }

        // ---- attention, per owned sample (wave-private, no barriers) ----
        #pragma unroll
        for (int smp = 0; smp < 2; ++smp){
            f32x4 sc = zero4;
            #pragma unroll
            for (int k0 = 0; k0 < DH; k0 += 32){
                bf16x8 qa = *(const bf16x8*)&QH(wid, smp, l15, k0 + g4 * 8);
                bf16x8 kb = *(const bf16x8*)&KH(wid, smp, l15, k0 + g4 * 8);
                sc = __builtin_amdgcn_mfma_f32_16x16x32_bf16(qa, kb, sc, 0, 0, 0);
            }
            f32x4 pr;
            #pragma unroll
            for (int r = 0; r < 4; ++r){
                float m = sc[r];
                m = fmaxf(m, __shfl_xor(m, 1)); m = fmaxf(m, __shfl_xor(m, 2));
                m = fmaxf(m, __shfl_xor(m, 4)); m = fmaxf(m, __shfl_xor(m, 8));
                float e = __expf(sc[r] - m);
                float ss = e;
                ss += __shfl_xor(ss, 1); ss += __shfl_xor(ss, 2);
                ss += __shfl_xor(ss, 4); ss += __shfl_xor(ss, 8);
                pr[r] = e / ss;
            }
            // P -> qh cols 0..15 (Q dead); pad keys 16..31 come from predicated zero regs
            #pragma unroll
            for (int r = 0; r < 4; ++r)
                QH(wid, smp, g4 * 4 + r, l15) = f2bf(pr[r]);

            // PV (K=32; keys 16..31 zero via predication: lane groups 2,3 keep zero regs)
            bf16x8 pa = zero8;
            if (g4 < 2) pa = *(const bf16x8*)&QH(wid, smp, l15, g4 * 8);
            #pragma unroll
            for (int nb = 0; nb < 4; ++nb){
                bf16x8 vb = zero8;
                if (g4 < 2) vb = *(const bf16x8*)&VT(wid, smp, nb * 16 + l15, g4 * 8);
                f32x4 at = __builtin_amdgcn_mfma_f32_16x16x32_bf16(pa, vb, zero4, 0, 0, 0);
                #pragma unroll
                for (int r = 0; r < 4; ++r)
                    KH(wid, smp, g4 * 4 + r, nb * 16 + l15) = f2bf(at[r]);
            }
            // store attn-out to aot[t][sample][k]: 16 x 64B segments per store op
            const size_t sg = (size_t)m32 * 2 + smp;
            #pragma unroll
            for (int kkl = 0; kkl < 2; ++kkl){
                bf16x8 o8 = *(const bf16x8*)&KH(wid, smp, l15, kkl * 32 + g4 * 8);
                *(bf16x8*)(aot + ((size_t)l15 * 4096 + sg) * 512 + hd * 64 + kkl * 32 + g4 * 8) = o8;
            }
        }
    }
    #undef STAGE_TO
}

// ---------------- kernel 3: fused O-proj + bias + residual + transpose-out ----------------
__global__ __launch_bounds__(256) void k_oproj_res(const u16* __restrict__ aot, const u16* __restrict__ wof,
                                                   const float* __restrict__ bo, const float* __restrict__ x,
                                                   float* __restrict__ out){
    __shared__ u16 atile[32 * 516];       // [sample][k], row stride 516 (2-way-free)
    __shared__ float otile[4][32 * 36];   // per-wave [c][w], row stride 36

    const int tid  = threadIdx.x;
    const int lane = tid & 63;
    const int wid  = tid >> 6;            // 0..3
    const int l31  = lane & 31;
    const int h32  = lane >> 5;
    int wg = blockIdx.x;                  // (b,h,t)
    int t = wg & 15, h = (wg >> 4) & 31, b = wg >> 9;
    const int s0 = (b * 32 + h) * 32;

    // stage A: 32 rows x 512 (32KB contiguous in aot) -> padded LDS (reg-staged)
    {
        const u16* src = aot + ((size_t)t * 4096 + s0) * 512;
        #pragma unroll
        for (int i = 0; i < 8; ++i){
            int flat = tid + 256 * i;          // 0..2047
            int row = flat >> 6, c16 = flat & 63;
            bf16x8 v = *(const bf16x8*)(src + (size_t)flat * 8);
            *(bf16x8*)(atile + row * 516 + c16 * 8) = v;
        }
    }
    __syncthreads();

    // wave's c-block range: 3/3/2/2
    const int nb_start = (wid < 2) ? wid * 3 : 6 + (wid - 2) * 2;
    const int nb_count = (wid < 2) ? 3 : 2;

    for (int j = 0; j < nb_count; ++j){
        const int nb = nb_start + j;
        f32x16 acc = (f32x16)Z16;
        const u16* wp = wof + ((size_t)(nb * 32) * 64 + lane) * 8;
        #pragma unroll
        for (int kt = 0; kt < 32; ++kt){
            bf16x8 af = *(const bf16x8*)(atile + l31 * 516 + kt * 16 + h32 * 8);
            bf16x8 bf = *(const bf16x8*)(wp + (size_t)kt * 512);
            acc = __builtin_amdgcn_mfma_f32_32x32x16_bf16(af, bf, acc, 0, 0, 0);
        }
        // C layout: col = l31 (c within block), row = (r&3)+8*(r>>2)+4*h32 (= w)
        float bias_v = bo[nb * 32 + l31];
        #pragma unroll
        for (int r = 0; r < 16; ++r){
            int row = (r & 3) + 8 * (r >> 2) + 4 * h32;
            otile[wid][l31 * 36 + row] = acc[r] + bias_v;
        }
        // residual + coalesced float4 write along w (same wave; compiler orders LDS RAW)
        int cl = lane >> 3;                   // 0..7
        int w4 = (lane & 7) * 4;
        #pragma unroll
        for (int ci = 0; ci < 4; ++ci){
            int c = ci * 8 + cl;
            size_t idx = ((size_t)(b * CC + nb * 32 + c) * TT + t) * 1024 + h * 32 + w4;
            f32x4 ov = *(const f32x4*)(&otile[wid][c * 36 + w4]);
            f32x4 xv = *(const f32x4*)(x + idx);
            *(f32x4*)(out + idx) = xv + ov;
        }
    }
}

extern "C" void kernel_launch(void* const* d_in, const int* in_sizes, int n_in,
                              void* d_out, int out_size, void* d_ws, size_t ws_size,
                              hipStream_t stream){
    const float* hid = (const float*)d_in[0];
    const float* lnw = (const float*)d_in[1];
    const float* lnb = (const float*)d_in[2];
    const float* Wq  = (const float*)d_in[3];
    const float* Wk  = (const float*)d_in[4];
    const float* Wv  = (const float*)d_in[5];
    const float* Wo  = (const float*)d_in[6];
    const float* bo  = (const float*)d_in[7];

    char* ws = (char*)d_ws;
    u16* wqkv = (u16*)ws;                                   // 960 frags * 512 = 491,520 elems
    u16* wo_f = wqkv + (size_t)960 * 512;                   // 320 frags * 512 = 163,840 elems
    u16* aot  = wo_f + 163840;                              // 16*4096*512 (67 MB), [t][sample][k]
    u16* xn   = aot + (size_t)TT * 4096 * INNER;            // 65536*320 (40 MB), 32-frag-major

    k_prep     <<<2368, 256, 0, stream>>>(Wq, Wk, Wv, Wo, lnw, lnb, hid, wqkv, wo_f, xn);
    k_attn     <<<256, 512, 0, stream>>>(xn, wqkv, aot);
    k_oproj_res<<<2048, 256, 0, stream>>>(aot, wo_f, bo, hid, (float*)d_out);
}